// Round 1
// baseline (867.718 us; speedup 1.0000x reference)
//
#include <hip/hip_runtime.h>
#include <math.h>

// LieNet round 4: (a) fused_kernel kt-loop double-buffered — one barrier per
// K-step, next tile's global_load_lds issued between frag ds_reads and MFMAs
// so the load latency hides under compute instead of draining at a barrier
// immediately after issue. (b) serial 512-step cumsum replaced by a 3-pass
// hierarchical scan (8 segments x 64 rows) to remove the latency-bound
// dependent chain at 1 wave/SIMD occupancy.
//
// Identity used (unchanged): bc[n-512] = gelu([h[n-256]|h[n]]@W+b) = the
// delta-blacket at row n, so each 64-row block computes D -> J1 -> P2 -> J2
// -> P3 -> J3 on-chip (P in LDS), one fp32 store of delta+J per row.

typedef unsigned short u16;
typedef __attribute__((ext_vector_type(8))) short short8;
typedef __attribute__((ext_vector_type(4))) float floatx4;

#define DD 256
#define PSTR 264          // P-lds row stride (elems): 528B -> 2-way-free banks
#define NCOL 65536        // scan columns = B*D
#define SEGS 8            // scan segments (64 s-steps each)

__device__ __forceinline__ float gelu_f(float v) {
    // tanh-form gelu; |err| vs exact erf-gelu ~3e-4, far under bf16 rounding
    float u = 0.7978845608028654f * v * (1.0f + 0.044715f * v * v);
    float e = __expf(2.0f * u);
    float t = 1.0f - 2.0f * __builtin_amdgcn_rcpf(e + 1.0f);
    return 0.5f * v * (1.0f + t);
}
__device__ __forceinline__ u16 bf_bits(float f) {
    __bf16 b = (__bf16)f;
    return __builtin_bit_cast(unsigned short, b);
}
__device__ __forceinline__ float bf2f(u16 u) {
    unsigned int x = ((unsigned int)u) << 16;
    return __builtin_bit_cast(float, x);
}

// ---------------- fused delta+J kernel ----------------
// Tile: 64 rows x 256 cols, 256 threads (4 waves), wave w owns cols [64w,64w+64).
// A/B frag: idx=lane&15, k=quad*8+e. C/D: col(n)=lane&15 path, row=quad*4+r
// (operand order identical to the round-2 kernel, HW-verified).
__global__ __launch_bounds__(256) void fused_kernel(
    const u16* __restrict__ h, const u16* __restrict__ W,   // W bf16 [256][512]
    const float* __restrict__ bias, float* __restrict__ out)
{
    __shared__ u16 Alds[2][64 * 32];     // double-buffered A K-slice
    __shared__ u16 Wlds[2][256 * 32];    // double-buffered W K-slice
    __shared__ u16 Plds[64 * PSTR];

    const int tid = threadIdx.x;
    const int w = tid >> 6, lane = tid & 63;
    const int quad = lane >> 4, lr = lane & 15;
    const long m0 = (long)blockIdx.x * 64;
    const bool has_x = (m0 >= 256);
    const bool has_J = (m0 >= 512);
    const int st_row = lane >> 2;             // staging row within 16-row chunk
    const int st_col = (lane & 3) * 8;        // staging col (elems)

    float bias_r[4];
    #pragma unroll
    for (int j = 0; j < 4; ++j) bias_r[j] = bias[w * 64 + j * 16 + lr];

    floatx4 Jacc[4][4];
    floatx4 acc[4][4];

    auto zero_acc = [&](floatx4 (&a)[4][4]) {
        floatx4 z = {0.f, 0.f, 0.f, 0.f};
        #pragma unroll
        for (int i = 0; i < 4; ++i)
            #pragma unroll
            for (int j = 0; j < 4; ++j) a[i][j] = z;
    };

    // Issue staging loads for K-slice kt into LDS buffer b (no barriers here).
    auto stage = [&](int kt, int b, long r0, bool zero0, long r1, bool fromP) {
        const int k0 = kt * 32;
        if (k0 < 256) {
            if (zero0) {
                short8 z = {0, 0, 0, 0, 0, 0, 0, 0};
                *(short8*)&Alds[b][(w * 16 + st_row) * 32 + st_col] = z;
            } else {
                const long g = (r0 + w * 16 + st_row) * DD + k0 + st_col;
                __builtin_amdgcn_global_load_lds(
                    (const __attribute__((address_space(1))) unsigned int*)(h + g),
                    (__attribute__((address_space(3))) unsigned int*)(&Alds[b][w * 16 * 32]),
                    16, 0, 0);
            }
        } else if (!fromP) {
            const long g = (r1 + w * 16 + st_row) * DD + (k0 - 256) + st_col;
            __builtin_amdgcn_global_load_lds(
                (const __attribute__((address_space(1))) unsigned int*)(h + g),
                (__attribute__((address_space(3))) unsigned int*)(&Alds[b][w * 16 * 32]),
                16, 0, 0);
        }
        #pragma unroll
        for (int i = 0; i < 4; ++i) {
            const long g = (long)(w * 64 + i * 16 + st_row) * 512 + k0 + st_col;
            __builtin_amdgcn_global_load_lds(
                (const __attribute__((address_space(1))) unsigned int*)(W + g),
                (__attribute__((address_space(3))) unsigned int*)(&Wlds[b][(w * 64 + i * 16) * 32]),
                16, 0, 0);
        }
    };

    // One 64x256xK=512 GEMM phase, double-buffered: barrier(kt) drains the
    // loads for slice kt (issued during iteration kt-1), so they overlap the
    // previous iteration's ds_reads + 16 MFMAs. One barrier per K-step.
    // Safety: buffer b^1 written by stage(kt+1) was last *read* before
    // barrier(kt) (its readers' lgkmcnt drained at that barrier); Plds
    // epilogue writes vs next-phase Plds reads are separated by >=8 barriers.
    auto gemm_phase = [&](long r0, bool zero0, long r1, bool fromP) {
        stage(0, 0, r0, zero0, r1, fromP);
        for (int kt = 0; kt < 16; ++kt) {
            const int b = kt & 1;
            const int k0 = kt * 32;
            __syncthreads();
            short8 af[4], bfr[4];
            const bool rdP = fromP && (k0 >= 256);
            #pragma unroll
            for (int i = 0; i < 4; ++i) {
                if (rdP) af[i] = *(const short8*)&Plds[(i * 16 + lr) * PSTR + (k0 - 256) + quad * 8];
                else     af[i] = *(const short8*)&Alds[b][(i * 16 + lr) * 32 + quad * 8];
            }
            #pragma unroll
            for (int j = 0; j < 4; ++j)
                bfr[j] = *(const short8*)&Wlds[b][(w * 64 + j * 16 + lr) * 32 + quad * 8];
            if (kt < 15) stage(kt + 1, b ^ 1, r0, zero0, r1, fromP);
            #pragma unroll
            for (int i = 0; i < 4; ++i)
                #pragma unroll
                for (int j = 0; j < 4; ++j)
                    acc[i][j] = __builtin_amdgcn_mfma_f32_16x16x32_bf16(af[i], bfr[j], acc[i][j], 0, 0, 0);
        }
    };

    auto add_gelu = [&]() {                    // Jacc += gelu(acc + bias)
        #pragma unroll
        for (int j = 0; j < 4; ++j)
            #pragma unroll
            for (int i = 0; i < 4; ++i)
                #pragma unroll
                for (int r = 0; r < 4; ++r)
                    Jacc[i][j][r] += gelu_f(acc[i][j][r] + bias_r[j]);
    };
    auto write_P = [&]() {                     // Plds = bf16(gelu(acc + bias))
        #pragma unroll
        for (int j = 0; j < 4; ++j) {
            const int n = w * 64 + j * 16 + lr;
            #pragma unroll
            for (int i = 0; i < 4; ++i)
                #pragma unroll
                for (int r = 0; r < 4; ++r)
                    Plds[(i * 16 + quad * 4 + r) * PSTR + n] =
                        bf_bits(gelu_f(acc[i][j][r] + bias_r[j]));
        }
    };

    // Phase D: G = gelu([b|c]@W+bias); P=G; Jacc = G + x  (b=x=h[m0-256], c=h[m0])
    zero_acc(acc);
    gemm_phase(m0 - 256, !has_x, m0, false);
    #pragma unroll
    for (int j = 0; j < 4; ++j) {
        const int n = w * 64 + j * 16 + lr;
        #pragma unroll
        for (int i = 0; i < 4; ++i) {
            const int rl = i * 16 + quad * 4;
            #pragma unroll
            for (int r = 0; r < 4; ++r) {
                float g = gelu_f(acc[i][j][r] + bias_r[j]);
                Plds[(rl + r) * PSTR + n] = bf_bits(g);
                float xv = has_x ? bf2f(h[(m0 - 256 + rl + r) * DD + n]) : 0.0f;
                Jacc[i][j][r] = g + xv;
            }
        }
    }

    if (has_J) {
        // J1: += gelu([a | P_bc]@W+bias),  a = h[m0-512]
        zero_acc(acc); gemm_phase(m0 - 512, false, 0, true);  add_gelu();
        // P2: ca = gelu([c | a]@W+bias)
        zero_acc(acc); gemm_phase(m0, false, m0 - 512, false); write_P();
        // J2: += gelu([b | P_ca]@W+bias)
        zero_acc(acc); gemm_phase(m0 - 256, false, 0, true);  add_gelu();
        // P3: ab = gelu([a | b]@W+bias)
        zero_acc(acc); gemm_phase(m0 - 512, false, m0 - 256, false); write_P();
        // J3: += gelu([c | P_ab]@W+bias)
        zero_acc(acc); gemm_phase(m0, false, 0, true);        add_gelu();
    }

    #pragma unroll
    for (int j = 0; j < 4; ++j) {
        const int n = w * 64 + j * 16 + lr;
        #pragma unroll
        for (int i = 0; i < 4; ++i) {
            const int rl = i * 16 + quad * 4;
            #pragma unroll
            for (int r = 0; r < 4; ++r)
                out[(m0 + rl + r) * DD + n] = Jacc[i][j][r];
        }
    }
}

// ---------------- h projection (round-2 structure, fp32 src -> bf16 h) ------
__global__ __launch_bounds__(256) void h_gemm(
    const float* __restrict__ src, const u16* __restrict__ Wm,  // Wm [256][256]
    const float* __restrict__ bias, u16* __restrict__ hout)
{
    __shared__ u16 Alds[128 * 32];
    __shared__ u16 Blds[128 * 32];

    const int tid = threadIdx.x;
    const int bm = blockIdx.x * 128;
    const int bn = blockIdx.y * 128;
    const int w = tid >> 6, lane = tid & 63;
    const int quad = lane >> 4, lr = lane & 15;
    const int wm = (w & 1) * 64, wn = (w >> 1) * 64;

    floatx4 acc[4][4];
    {
        floatx4 z = {0.f, 0.f, 0.f, 0.f};
        #pragma unroll
        for (int i = 0; i < 4; ++i)
            #pragma unroll
            for (int j = 0; j < 4; ++j) acc[i][j] = z;
    }

    for (int k0 = 0; k0 < 256; k0 += 32) {
        __syncthreads();
        #pragma unroll
        for (int i = 0; i < 2; ++i) {          // A: fp32 load + convert
            const int row = w * 32 + i * 16 + (lane >> 2);
            const long g = (long)(bm + row) * DD + k0 + (lane & 3) * 8;
            floatx4 f0 = *(const floatx4*)(src + g);
            floatx4 f1 = *(const floatx4*)(src + g + 4);
            short8 v;
            #pragma unroll
            for (int e = 0; e < 4; ++e) {
                v[e]     = (short)bf_bits(f0[e]);
                v[e + 4] = (short)bf_bits(f1[e]);
            }
            *(short8*)&Alds[row * 32 + (lane & 3) * 8] = v;
        }
        #pragma unroll
        for (int i = 0; i < 2; ++i) {          // W tile
            const int row = w * 32 + i * 16 + (lane >> 2);
            const long g = (long)(bn + row) * DD + k0 + (lane & 3) * 8;
            __builtin_amdgcn_global_load_lds(
                (const __attribute__((address_space(1))) unsigned int*)(Wm + g),
                (__attribute__((address_space(3))) unsigned int*)(Blds + (w * 32 + i * 16) * 32),
                16, 0, 0);
        }
        __syncthreads();

        short8 af[4], bfr[4];
        #pragma unroll
        for (int i = 0; i < 4; ++i)
            af[i] = *(const short8*)&Alds[(wm + i * 16 + lr) * 32 + quad * 8];
        #pragma unroll
        for (int j = 0; j < 4; ++j)
            bfr[j] = *(const short8*)&Blds[(wn + j * 16 + lr) * 32 + quad * 8];
        #pragma unroll
        for (int i = 0; i < 4; ++i)
            #pragma unroll
            for (int j = 0; j < 4; ++j)
                acc[i][j] = __builtin_amdgcn_mfma_f32_16x16x32_bf16(af[i], bfr[j], acc[i][j], 0, 0, 0);
    }

    #pragma unroll
    for (int j = 0; j < 4; ++j) {
        const int n = bn + wn + j * 16 + lr;
        const float bv = bias[n];
        #pragma unroll
        for (int i = 0; i < 4; ++i) {
            const int m = bm + wm + i * 16 + quad * 4;
            #pragma unroll
            for (int r = 0; r < 4; ++r)
                hout[(long)(m + r) * DD + n] = bf_bits(gelu_f(acc[i][j][r] + bv));
        }
    }
}

// fp32 -> bf16 of map_w (65536) then bl_w (131072)
__global__ __launch_bounds__(256) void conv_w(const float* __restrict__ mw,
                                              const float* __restrict__ bw,
                                              u16* __restrict__ outw)
{
    const int i = blockIdx.x * 256 + threadIdx.x;
    outw[i] = (i < 65536) ? bf_bits(mw[i]) : bf_bits(bw[i - 65536]);
}

// ---------------- hierarchical cumsum over s (512 rows x 65536 cols) --------
// Pass 1: per-segment sums (8 segs x 64 rows). 2048 blocks -> full occupancy,
// 64-deep independent-address load chain pipelines under unroll.
__global__ __launch_bounds__(256) void seg_sum_kernel(
    const float* __restrict__ out, float* __restrict__ sums)
{
    const int idx = blockIdx.x * 256 + threadIdx.x;      // 0..524287
    const int seg = idx >> 16, col = idx & (NCOL - 1);
    const float* p = out + (long)seg * 64 * NCOL + col;
    float a = 0.f;
    #pragma unroll 8
    for (int s = 0; s < 64; ++s) a += p[(long)s * NCOL];
    sums[seg * NCOL + col] = a;
}

// Pass 2: exclusive scan of the 8 segment sums per column.
__global__ __launch_bounds__(256) void seg_offset_kernel(float* __restrict__ sums)
{
    const int col = blockIdx.x * 256 + threadIdx.x;
    float a = 0.f;
    #pragma unroll
    for (int g = 0; g < SEGS; ++g) {
        float v = sums[g * NCOL + col];
        sums[g * NCOL + col] = a;
        a += v;
    }
}

// Pass 3: in-segment running sum + segment offset, written in place.
__global__ __launch_bounds__(256) void seg_apply_kernel(
    float* __restrict__ out, const float* __restrict__ sums)
{
    const int idx = blockIdx.x * 256 + threadIdx.x;
    const int seg = idx >> 16, col = idx & (NCOL - 1);
    float a = sums[seg * NCOL + col];
    float* p = out + (long)seg * 64 * NCOL + col;
    #pragma unroll 8
    for (int s = 0; s < 64; ++s) {
        a += p[(long)s * NCOL];
        p[(long)s * NCOL] = a;
    }
}

extern "C" void kernel_launch(void* const* d_in, const int* in_sizes, int n_in,
                              void* d_out, int out_size, void* d_ws, size_t ws_size,
                              hipStream_t stream)
{
    const float* src   = (const float*)d_in[0];
    const float* map_w = (const float*)d_in[1];
    const float* map_b = (const float*)d_in[2];
    const float* bl_w  = (const float*)d_in[3];
    const float* bl_b  = (const float*)d_in[4];
    float* out = (float*)d_out;

    const int SB = 512 * 256;                 // 131072 rows

    u16* h_bf = (u16*)d_ws;                   // 64 MB
    u16* wbuf = h_bf + (long)SB * DD;         // 196608 u16
    u16* wmap = wbuf;
    u16* wbl  = wbuf + 65536;
    float* sums = (float*)(wbuf + 196608);    // 2 MB scan scratch

    const dim3 blk(256);

    conv_w<<<dim3(768), blk, 0, stream>>>(map_w, bl_w, wbuf);
    h_gemm<<<dim3(SB / 128, 2), blk, 0, stream>>>(src, wmap, map_b, h_bf);
    fused_kernel<<<dim3(SB / 64), blk, 0, stream>>>(h_bf, wbl, bl_b, out);
    seg_sum_kernel<<<dim3(SEGS * NCOL / 256), blk, 0, stream>>>(out, sums);
    seg_offset_kernel<<<dim3(NCOL / 256), blk, 0, stream>>>(sums);
    seg_apply_kernel<<<dim3(SEGS * NCOL / 256), blk, 0, stream>>>(out, sums);
}

// Round 2
// 833.143 us; speedup vs baseline: 1.0415x; 1.0415x over previous
//
#include <hip/hip_runtime.h>
#include <math.h>

// LieNet round 5: fused_kernel K-loop rebuilt on the T3+T4 template —
// triple-buffered LDS, depth-2 prefetch, raw s_barrier + counted
// s_waitcnt vmcnt(5) (never drained to 0 in the main loop). Every K-slice
// issues exactly 5 global_load_lds (1 A + 4 W) in every phase variant so the
// vmcnt arithmetic is uniform: fromP phases issue an L1-hot dummy A-load for
// slices >=8; zero-fill (blocks 0-3) pre-zeros the A buffers once and sends
// the dummy into then-dead Plds. Scan + h_gemm unchanged from round 4.
//
// Identity used (unchanged): bc[n-512] = gelu([h[n-256]|h[n]]@W+b) = the
// delta-blacket at row n, so each 64-row block computes D -> J1 -> P2 -> J2
// -> P3 -> J3 on-chip (P in LDS), one fp32 store of delta+J per row.

typedef unsigned short u16;
typedef __attribute__((ext_vector_type(8))) short short8;
typedef __attribute__((ext_vector_type(4))) float floatx4;

#define DD 256
#define PSTR 264          // P-lds row stride (elems): 528B -> 2-way-free banks
#define NCOL 65536        // scan columns = B*D
#define SEGS 8            // scan segments (64 s-steps each)

__device__ __forceinline__ float gelu_f(float v) {
    // tanh-form gelu; |err| vs exact erf-gelu ~3e-4, far under bf16 rounding
    float u = 0.7978845608028654f * v * (1.0f + 0.044715f * v * v);
    float e = __expf(2.0f * u);
    float t = 1.0f - 2.0f * __builtin_amdgcn_rcpf(e + 1.0f);
    return 0.5f * v * (1.0f + t);
}
__device__ __forceinline__ u16 bf_bits(float f) {
    __bf16 b = (__bf16)f;
    return __builtin_bit_cast(unsigned short, b);
}
__device__ __forceinline__ float bf2f(u16 u) {
    unsigned int x = ((unsigned int)u) << 16;
    return __builtin_bit_cast(float, x);
}

#define AS1(p) ((const __attribute__((address_space(1))) unsigned int*)(p))
#define AS3(p) ((__attribute__((address_space(3))) unsigned int*)(p))

// ---------------- fused delta+J kernel ----------------
// Tile: 64 rows x 256 cols, 256 threads (4 waves), wave w owns cols [64w,64w+64).
// A/B frag: idx=lane&15, k=quad*8+e. C/D: col(n)=lane&15 path, row=quad*4+r
// (operand order identical to the round-2 kernel, HW-verified).
__global__ __launch_bounds__(256) void fused_kernel(
    const u16* __restrict__ h, const u16* __restrict__ W,   // W bf16 [256][512]
    const float* __restrict__ bias, float* __restrict__ out)
{
    __shared__ u16 Alds[3][64 * 32];     // triple-buffered A K-slice (12 KB)
    __shared__ u16 Wlds[3][256 * 32];    // triple-buffered W K-slice (48 KB)
    __shared__ u16 Plds[64 * PSTR];      // 33.75 KB

    const int tid = threadIdx.x;
    const int w = tid >> 6, lane = tid & 63;
    const int quad = lane >> 4, lr = lane & 15;
    const long m0 = (long)blockIdx.x * 64;
    const bool has_x = (m0 >= 256);
    const bool has_J = (m0 >= 512);
    const int st_row = lane >> 2;             // staging row within 16-row chunk
    const int st_col = (lane & 3) * 8;        // staging col (elems)

    float bias_r[4];
    #pragma unroll
    for (int j = 0; j < 4; ++j) bias_r[j] = bias[w * 64 + j * 16 + lr];

    floatx4 Jacc[4][4];
    floatx4 acc[4][4];

    auto zero_acc = [&](floatx4 (&a)[4][4]) {
        floatx4 z = {0.f, 0.f, 0.f, 0.f};
        #pragma unroll
        for (int i = 0; i < 4; ++i)
            #pragma unroll
            for (int j = 0; j < 4; ++j) a[i][j] = z;
    };

    // Issue the 5 staging loads for K-slice s into LDS buffer s%3.
    // Always exactly 5 global_load_lds so counted vmcnt is phase-invariant.
    auto stage = [&](int s, long r0, bool zero0, long r1, bool fromP) {
        const int k0 = s * 32;
        const int b  = s % 3;
        const u16* srcA;
        u16* dstA;
        if (k0 < 256) {
            if (zero0) {                       // dummy: A stays pre-zeroed
                srcA = h + (m0 + w * 16 + st_row) * DD + st_col;   // L1-hot
                dstA = Plds + w * 512;         // Plds dead during phase D
            } else {
                srcA = h + (r0 + w * 16 + st_row) * DD + k0 + st_col;
                dstA = &Alds[b][w * 16 * 32];
            }
        } else if (fromP) {                    // dummy: frags come from Plds
            srcA = h + (m0 + w * 16 + st_row) * DD + st_col;       // L1-hot
            dstA = &Alds[b][w * 16 * 32];      // dead slot, never read
        } else {
            srcA = h + (r1 + w * 16 + st_row) * DD + (k0 - 256) + st_col;
            dstA = &Alds[b][w * 16 * 32];
        }
        __builtin_amdgcn_global_load_lds(AS1(srcA), AS3(dstA), 16, 0, 0);
        #pragma unroll
        for (int i = 0; i < 4; ++i) {
            const long g = (long)(w * 64 + i * 16 + st_row) * 512 + k0 + st_col;
            __builtin_amdgcn_global_load_lds(
                AS1(W + g), AS3(&Wlds[b][(w * 64 + i * 16) * 32]), 16, 0, 0);
        }
    };

    // One 64x256xK=512 GEMM phase. Depth-2 prefetch: slice kt's loads are
    // issued at iter kt-2, waited with vmcnt(5) (slice kt done, kt+1 still in
    // flight) at iter kt. s_barrier then publishes all waves' LDS writes.
    // Buffer safety: stage(kt+2) overwrites buf[(kt-1)%3], whose readers
    // finished (lgkmcnt-drained before their MFMAs) before barrier(kt).
    auto gemm_phase = [&](long r0, bool zero0, long r1, bool fromP) {
        __syncthreads();                       // phase boundary: full drain
        stage(0, r0, zero0, r1, fromP);
        stage(1, r0, zero0, r1, fromP);
        #pragma unroll
        for (int kt = 0; kt < 16; ++kt) {
            const int b = kt % 3;
            const int k0 = kt * 32;
            if (kt < 15) asm volatile("s_waitcnt vmcnt(5)" ::: "memory");
            else         asm volatile("s_waitcnt vmcnt(0)" ::: "memory");
            __builtin_amdgcn_s_barrier();
            __builtin_amdgcn_sched_barrier(0);
            if (kt + 2 < 16) stage(kt + 2, r0, zero0, r1, fromP);
            short8 af[4], bfr[4];
            const bool rdP = fromP && (k0 >= 256);
            #pragma unroll
            for (int i = 0; i < 4; ++i) {
                if (rdP) af[i] = *(const short8*)&Plds[(i * 16 + lr) * PSTR + (k0 - 256) + quad * 8];
                else     af[i] = *(const short8*)&Alds[b][(i * 16 + lr) * 32 + quad * 8];
            }
            #pragma unroll
            for (int j = 0; j < 4; ++j)
                bfr[j] = *(const short8*)&Wlds[b][(w * 64 + j * 16 + lr) * 32 + quad * 8];
            #pragma unroll
            for (int i = 0; i < 4; ++i)
                #pragma unroll
                for (int j = 0; j < 4; ++j)
                    acc[i][j] = __builtin_amdgcn_mfma_f32_16x16x32_bf16(af[i], bfr[j], acc[i][j], 0, 0, 0);
        }
    };

    auto add_gelu = [&]() {                    // Jacc += gelu(acc + bias)
        #pragma unroll
        for (int j = 0; j < 4; ++j)
            #pragma unroll
            for (int i = 0; i < 4; ++i)
                #pragma unroll
                for (int r = 0; r < 4; ++r)
                    Jacc[i][j][r] += gelu_f(acc[i][j][r] + bias_r[j]);
    };
    auto write_P = [&]() {                     // Plds = bf16(gelu(acc + bias))
        #pragma unroll
        for (int j = 0; j < 4; ++j) {
            const int n = w * 64 + j * 16 + lr;
            #pragma unroll
            for (int i = 0; i < 4; ++i)
                #pragma unroll
                for (int r = 0; r < 4; ++r)
                    Plds[(i * 16 + quad * 4 + r) * PSTR + n] =
                        bf_bits(gelu_f(acc[i][j][r] + bias_r[j]));
        }
    };

    // Blocks 0-3: pre-zero all 3 A buffers once; stage() then never writes
    // A during slices 0-7 of phase D (dummy goes to Plds), buffers stay zero.
    if (!has_x) {
        short8 z = {0, 0, 0, 0, 0, 0, 0, 0};
        #pragma unroll
        for (int b = 0; b < 3; ++b)
            *(short8*)&Alds[b][tid * 8] = z;   // 256 thr x 8 u16 = 2048 u16/buf
        asm volatile("s_waitcnt lgkmcnt(0)" ::: "memory");
    }

    // Phase D: G = gelu([b|c]@W+bias); P=G; Jacc = G + x  (b=x=h[m0-256], c=h[m0])
    zero_acc(acc);
    gemm_phase(m0 - 256, !has_x, m0, false);
    #pragma unroll
    for (int j = 0; j < 4; ++j) {
        const int n = w * 64 + j * 16 + lr;
        #pragma unroll
        for (int i = 0; i < 4; ++i) {
            const int rl = i * 16 + quad * 4;
            #pragma unroll
            for (int r = 0; r < 4; ++r) {
                float g = gelu_f(acc[i][j][r] + bias_r[j]);
                Plds[(rl + r) * PSTR + n] = bf_bits(g);
                float xv = has_x ? bf2f(h[(m0 - 256 + rl + r) * DD + n]) : 0.0f;
                Jacc[i][j][r] = g + xv;
            }
        }
    }

    if (has_J) {
        // J1: += gelu([a | P_bc]@W+bias),  a = h[m0-512]
        zero_acc(acc); gemm_phase(m0 - 512, false, m0, true);   add_gelu();
        // P2: ca = gelu([c | a]@W+bias)
        zero_acc(acc); gemm_phase(m0, false, m0 - 512, false);  write_P();
        // J2: += gelu([b | P_ca]@W+bias)
        zero_acc(acc); gemm_phase(m0 - 256, false, m0, true);   add_gelu();
        // P3: ab = gelu([a | b]@W+bias)
        zero_acc(acc); gemm_phase(m0 - 512, false, m0 - 256, false); write_P();
        // J3: += gelu([c | P_ab]@W+bias)
        zero_acc(acc); gemm_phase(m0, false, m0, true);         add_gelu();
    }

    #pragma unroll
    for (int j = 0; j < 4; ++j) {
        const int n = w * 64 + j * 16 + lr;
        #pragma unroll
        for (int i = 0; i < 4; ++i) {
            const int rl = i * 16 + quad * 4;
            #pragma unroll
            for (int r = 0; r < 4; ++r)
                out[(m0 + rl + r) * DD + n] = Jacc[i][j][r];
        }
    }
}

// ---------------- h projection (round-2 structure, fp32 src -> bf16 h) ------
__global__ __launch_bounds__(256) void h_gemm(
    const float* __restrict__ src, const u16* __restrict__ Wm,  // Wm [256][256]
    const float* __restrict__ bias, u16* __restrict__ hout)
{
    __shared__ u16 Alds[128 * 32];
    __shared__ u16 Blds[128 * 32];

    const int tid = threadIdx.x;
    const int bm = blockIdx.x * 128;
    const int bn = blockIdx.y * 128;
    const int w = tid >> 6, lane = tid & 63;
    const int quad = lane >> 4, lr = lane & 15;
    const int wm = (w & 1) * 64, wn = (w >> 1) * 64;

    floatx4 acc[4][4];
    {
        floatx4 z = {0.f, 0.f, 0.f, 0.f};
        #pragma unroll
        for (int i = 0; i < 4; ++i)
            #pragma unroll
            for (int j = 0; j < 4; ++j) acc[i][j] = z;
    }

    for (int k0 = 0; k0 < 256; k0 += 32) {
        __syncthreads();
        #pragma unroll
        for (int i = 0; i < 2; ++i) {          // A: fp32 load + convert
            const int row = w * 32 + i * 16 + (lane >> 2);
            const long g = (long)(bm + row) * DD + k0 + (lane & 3) * 8;
            floatx4 f0 = *(const floatx4*)(src + g);
            floatx4 f1 = *(const floatx4*)(src + g + 4);
            short8 v;
            #pragma unroll
            for (int e = 0; e < 4; ++e) {
                v[e]     = (short)bf_bits(f0[e]);
                v[e + 4] = (short)bf_bits(f1[e]);
            }
            *(short8*)&Alds[row * 32 + (lane & 3) * 8] = v;
        }
        #pragma unroll
        for (int i = 0; i < 2; ++i) {          // W tile
            const int row = w * 32 + i * 16 + (lane >> 2);
            const long g = (long)(bn + row) * DD + k0 + (lane & 3) * 8;
            __builtin_amdgcn_global_load_lds(
                AS1(Wm + g), AS3(Blds + (w * 32 + i * 16) * 32), 16, 0, 0);
        }
        __syncthreads();

        short8 af[4], bfr[4];
        #pragma unroll
        for (int i = 0; i < 4; ++i)
            af[i] = *(const short8*)&Alds[(wm + i * 16 + lr) * 32 + quad * 8];
        #pragma unroll
        for (int j = 0; j < 4; ++j)
            bfr[j] = *(const short8*)&Blds[(wn + j * 16 + lr) * 32 + quad * 8];
        #pragma unroll
        for (int i = 0; i < 4; ++i)
            #pragma unroll
            for (int j = 0; j < 4; ++j)
                acc[i][j] = __builtin_amdgcn_mfma_f32_16x16x32_bf16(af[i], bfr[j], acc[i][j], 0, 0, 0);
    }

    #pragma unroll
    for (int j = 0; j < 4; ++j) {
        const int n = bn + wn + j * 16 + lr;
        const float bv = bias[n];
        #pragma unroll
        for (int i = 0; i < 4; ++i) {
            const int m = bm + wm + i * 16 + quad * 4;
            #pragma unroll
            for (int r = 0; r < 4; ++r)
                hout[(long)(m + r) * DD + n] = bf_bits(gelu_f(acc[i][j][r] + bv));
        }
    }
}

// fp32 -> bf16 of map_w (65536) then bl_w (131072)
__global__ __launch_bounds__(256) void conv_w(const float* __restrict__ mw,
                                              const float* __restrict__ bw,
                                              u16* __restrict__ outw)
{
    const int i = blockIdx.x * 256 + threadIdx.x;
    outw[i] = (i < 65536) ? bf_bits(mw[i]) : bf_bits(bw[i - 65536]);
}

// ---------------- hierarchical cumsum over s (512 rows x 65536 cols) --------
// Pass 1: per-segment sums (8 segs x 64 rows).
__global__ __launch_bounds__(256) void seg_sum_kernel(
    const float* __restrict__ out, float* __restrict__ sums)
{
    const int idx = blockIdx.x * 256 + threadIdx.x;      // 0..524287
    const int seg = idx >> 16, col = idx & (NCOL - 1);
    const float* p = out + (long)seg * 64 * NCOL + col;
    float a = 0.f;
    #pragma unroll 8
    for (int s = 0; s < 64; ++s) a += p[(long)s * NCOL];
    sums[seg * NCOL + col] = a;
}

// Pass 2: exclusive scan of the 8 segment sums per column.
__global__ __launch_bounds__(256) void seg_offset_kernel(float* __restrict__ sums)
{
    const int col = blockIdx.x * 256 + threadIdx.x;
    float a = 0.f;
    #pragma unroll
    for (int g = 0; g < SEGS; ++g) {
        float v = sums[g * NCOL + col];
        sums[g * NCOL + col] = a;
        a += v;
    }
}

// Pass 3: in-segment running sum + segment offset, written in place.
__global__ __launch_bounds__(256) void seg_apply_kernel(
    float* __restrict__ out, const float* __restrict__ sums)
{
    const int idx = blockIdx.x * 256 + threadIdx.x;
    const int seg = idx >> 16, col = idx & (NCOL - 1);
    float a = sums[seg * NCOL + col];
    float* p = out + (long)seg * 64 * NCOL + col;
    #pragma unroll 8
    for (int s = 0; s < 64; ++s) {
        a += p[(long)s * NCOL];
        p[(long)s * NCOL] = a;
    }
}

extern "C" void kernel_launch(void* const* d_in, const int* in_sizes, int n_in,
                              void* d_out, int out_size, void* d_ws, size_t ws_size,
                              hipStream_t stream)
{
    const float* src   = (const float*)d_in[0];
    const float* map_w = (const float*)d_in[1];
    const float* map_b = (const float*)d_in[2];
    const float* bl_w  = (const float*)d_in[3];
    const float* bl_b  = (const float*)d_in[4];
    float* out = (float*)d_out;

    const int SB = 512 * 256;                 // 131072 rows

    u16* h_bf = (u16*)d_ws;                   // 64 MB
    u16* wbuf = h_bf + (long)SB * DD;         // 196608 u16
    u16* wmap = wbuf;
    u16* wbl  = wbuf + 65536;
    float* sums = (float*)(wbuf + 196608);    // 2 MB scan scratch

    const dim3 blk(256);

    conv_w<<<dim3(768), blk, 0, stream>>>(map_w, bl_w, wbuf);
    h_gemm<<<dim3(SB / 128, 2), blk, 0, stream>>>(src, wmap, map_b, h_bf);
    fused_kernel<<<dim3(SB / 64), blk, 0, stream>>>(h_bf, wbl, bl_b, out);
    seg_sum_kernel<<<dim3(SEGS * NCOL / 256), blk, 0, stream>>>(out, sums);
    seg_offset_kernel<<<dim3(NCOL / 256), blk, 0, stream>>>(sums);
    seg_apply_kernel<<<dim3(SEGS * NCOL / 256), blk, 0, stream>>>(out, sums);
}